// Round 23
// baseline (457.313 us; speedup 1.0000x reference)
//
#include <hip/hip_runtime.h>

#define DEV __device__ __forceinline__
#define SBAR() __builtin_amdgcn_sched_barrier(0)

typedef _Float16 half8 __attribute__((ext_vector_type(8)));
typedef _Float16 half2v __attribute__((ext_vector_type(2)));
typedef float f32x16 __attribute__((ext_vector_type(16)));
typedef int int4v __attribute__((ext_vector_type(4)));

DEV f32x16 mfma16(half8 a, half8 b, f32x16 c) {
    return __builtin_amdgcn_mfma_f32_32x32x16_f16(a, b, c, 0, 0, 0);
}
DEV half8 h8(int4v v) { return __builtin_bit_cast(half8, v); }
DEV half8 ldh8(const _Float16* p) { return *(const half8*)p; }
DEV int pkrtz(float a, float b) {
    auto t = __builtin_amdgcn_cvt_pkrtz(a, b);
    return __builtin_bit_cast(int, t);
}
// pack two f32 -> f16x2 (RTZ), then packed relu
DEV int relupk(float a, float b) {
    int p = pkrtz(a, b);
    half2v h = __builtin_bit_cast(half2v, p);
    half2v z = {(_Float16)0.f, (_Float16)0.f};
    h = __builtin_elementwise_max(h, z);   // v_pk_max_f16
    return __builtin_bit_cast(int, h);
}

DEV f32x16 zero16() {
    f32x16 z = {0.f,0.f,0.f,0.f,0.f,0.f,0.f,0.f,0.f,0.f,0.f,0.f,0.f,0.f,0.f,0.f};
    return z;
}

struct Frags { int4v c[4]; };  // activation B-fragments, K=64 (4 chunks of 16)

// sigma-repack (verified R18): weights' k-rows permuted by the involution
// sigma(k)=(k&3)+8*((k&7)>>2)+4*(k>>3) -> D-layout IS the next B-frag layout after pack.
DEV void repack(const f32x16& C0, const f32x16& C1, Frags& B) {
    int4v b0, b1, b2, b3;
#pragma unroll
    for (int q = 0; q < 4; ++q) {
        b0[q] = relupk(C0[2*q],     C0[2*q+1]);
        b1[q] = relupk(C0[8+2*q],   C0[9+2*q]);
        b2[q] = relupk(C1[2*q],     C1[2*q+1]);
        b3[q] = relupk(C1[8+2*q],   C1[9+2*q]);
    }
    B.c[0] = b0; B.c[1] = b1; B.c[2] = b2; B.c[3] = b3;
}

// 8 ds_read_b128: one hidden layer's A-fragments (4 chunks x 2 m-halves; no bias chunk)
DEV void loadA4(const _Float16* base, int lam, half8* A0, half8* A1) {
    const _Float16* p0 = base + lam * 8;
    const _Float16* p1 = base + 2048 + lam * 8;
#pragma unroll
    for (int kk = 0; kk < 4; ++kk) {
        A0[kk] = ldh8(p0 + kk * 512);
        A1[kk] = ldh8(p1 + kk * 512);
    }
}

// load layer-l bias fragment into ping-pong registers (f32 D-layout, broadcast reads).
DEV void biasLoad(const float* bD, int l, int h, f32x16& n0, f32x16& n1) {
    const float* p = bD + l * 64 + h * 16;
#pragma unroll
    for (int i = 0; i < 4; ++i) {
        float4 a = *(const float4*)(p + 4 * i);
        float4 b = *(const float4*)(p + 32 + 4 * i);
        n0[4*i+0] = a.x; n0[4*i+1] = a.y; n0[4*i+2] = a.z; n0[4*i+3] = a.w;
        n1[4*i+0] = b.x; n1[4*i+1] = b.y; n1[4*i+2] = b.z; n1[4*i+3] = b.w;
    }
}

// hidden layer burst: 8 MFMA, C-in of the first pair = prefetched bias (nb preserved
// so both streams can consume the same bias buffer)
DEV void mfma_hid4b(const half8* A0, const half8* A1, const Frags& Bx,
                    const f32x16& n0, const f32x16& n1, f32x16& C0, f32x16& C1) {
    __builtin_amdgcn_s_setprio(1);
    half8 b0 = h8(Bx.c[0]);
    C0 = mfma16(A0[0], b0, n0);
    C1 = mfma16(A1[0], b0, n1);
#pragma unroll
    for (int kk = 1; kk < 4; ++kk) {
        half8 b = h8(Bx.c[kk]);
        C0 = mfma16(A0[kk], b, C0);
        C1 = mfma16(A1[kk], b, C1);
    }
    __builtin_amdgcn_s_setprio(0);
}

// input layer burst: K=32 (b_in rides in x's k=28 slot), 4 MFMA, zero C-init
DEV void mfma_in_t(const half8* I, const Frags& Bx, f32x16& C0, f32x16& C1) {
    __builtin_amdgcn_s_setprio(1);
    C0 = mfma16(I[0], h8(Bx.c[0]), zero16());
    C1 = mfma16(I[2], h8(Bx.c[0]), zero16());
    C0 = mfma16(I[1], h8(Bx.c[1]), C0);
    C1 = mfma16(I[3], h8(Bx.c[1]), C1);
    __builtin_amdgcn_s_setprio(0);
}

// out layer burst: 4 MFMA, C-init = hoisted b_out fragment bo
DEV void mfma_out4(const half8* Ao, const Frags& Bx, const f32x16& bo, f32x16& C) {
    __builtin_amdgcn_s_setprio(1);
    C = mfma16(Ao[0], h8(Bx.c[0]), bo);
#pragma unroll
    for (int kk = 1; kk < 4; ++kk) C = mfma16(Ao[kk], h8(Bx.c[kk]), C);
    __builtin_amdgcn_s_setprio(0);
}

DEV void store_out(const f32x16& C, int h, float* __restrict__ out, int row) {
    float* o = out + row * 21;
#pragma unroll
    for (int r = 0; r < 16; ++r) {
        int f = (r & 3) + 8 * (r >> 2) + 4 * h;
        if (f < 21) o[f] = __builtin_amdgcn_rcpf(1.f + __expf(-C[r]));
    }
}

DEV void load_x(const float* __restrict__ x, int row, int h, Frags& B) {
    // identity k-order (wI stored identity); k=28 slot carries 1.0 (bias rides in wI row 28)
    const float* xr = x + row * 28;
    float4 fa = *(const float4*)(xr + 8 * h);
    float4 fb = *(const float4*)(xr + 8 * h + 4);
    float4 fc = *(const float4*)(xr + 16 + 8 * h);
    float4 fd = (h == 0) ? *(const float4*)(xr + 20) : make_float4(1.f, 0.f, 0.f, 0.f);
    int4v c0, c1;
    c0[0] = pkrtz(fa.x, fa.y); c0[1] = pkrtz(fa.z, fa.w);
    c0[2] = pkrtz(fb.x, fb.y); c0[3] = pkrtz(fb.z, fb.w);
    c1[0] = pkrtz(fc.x, fc.y); c1[1] = pkrtz(fc.z, fc.w);
    c1[2] = pkrtz(fd.x, fd.y); c1[3] = pkrtz(fd.z, fd.w);
    B.c[0] = c0; B.c[1] = c1;
}

#define NT 768

// 3 waves/SIMD (170-reg budget >= current 128-reg footprint): more cross-wave overlap
// (R21: 2->1 waves cost 1.59x, so overlap is the operative mechanism) without the
// 4-wave-era register squeeze.
__global__ __attribute__((amdgpu_flat_work_group_size(NT, NT), amdgpu_waves_per_eu(3, 3)))
void mlp_fused(
    const float* __restrict__ x, const float* __restrict__ W_in, const float* __restrict__ b_in,
    const float* __restrict__ W_hid, const float* __restrict__ b_hid,
    const float* __restrict__ W_out, const float* __restrict__ b_out,
    float* __restrict__ out) {
    // LDS weights in f16, A-fragment order, SIGMA-permuted k (wI identity-k).
    __shared__ __align__(16) _Float16 wH[40960];  // 10 x 2 x 4 x 64 x 8 = 80 KB
    __shared__ __align__(16) _Float16 wI[2048];   // 2 x 2 x 64 x 8  (K=32, b_in in k=28)
    __shared__ __align__(16) _Float16 wO[2048];   // 4 x 64 x 8      (features 0..20)
    __shared__ __align__(16) float biasD[640];    // [l][half][h][r] f32 D-layout
    __shared__ __align__(16) float biasOut[32];   // [h][r] f32 D-layout

    const int tid = threadIdx.x;

    // zero phase (wH, biasD, biasOut are fully written by fill)
    for (int i = tid; i < 2048; i += NT) { wI[i] = (_Float16)0.f; wO[i] = (_Float16)0.f; }
    __syncthreads();

    // fill phase (coalesced global reads, scattered LDS writes)
    for (int i = tid; i < 40960; i += NT) {   // W_hid [l][kin][o], sigma-permuted k
        int o = i & 63, kin = (i >> 6) & 63, l = i >> 12;
        int m = o >> 5, kk = kin >> 4;
        int hh = (kin >> 2) & 1;
        int e = (kin & 3) + 4 * ((kin >> 3) & 1);
        int lam = hh * 32 + (o & 31);
        wH[l * 4096 + m * 2048 + kk * 512 + lam * 8 + e] = (_Float16)W_hid[i];
    }
    for (int i = tid; i < 640; i += NT) {     // b_hid -> f32 D-layout [l][half][h][r]
        int l = i >> 6, f = i & 63;
        int half = f >> 5, fin = f & 31;
        int hh = (fin >> 2) & 1, r = (fin & 3) + 4 * (fin >> 3);
        biasD[l * 64 + half * 32 + hh * 16 + r] = b_hid[i];
    }
    for (int i = tid; i < 1792; i += NT) {    // W_in [28][64], identity k
        int o = i & 63, kin = i >> 6;
        int m = o >> 5, kk = kin >> 4, hh = (kin >> 3) & 1, e = kin & 7;
        int lam = hh * 32 + (o & 31);
        wI[m * 1024 + kk * 512 + lam * 8 + e] = (_Float16)W_in[i];
    }
    for (int i = tid; i < 64; i += NT) {      // b_in -> wI k=28 slot: kk=1, hh=1, e=4
        int m = i >> 5;
        wI[m * 1024 + 512 + (32 + (i & 31)) * 8 + 4] = (_Float16)b_in[i];
    }
    for (int i = tid; i < 1344; i += NT) {    // W_out [64][21], sigma-permuted k
        int o = i % 21, kin = i / 21;
        int kk = kin >> 4;
        int hh = (kin >> 2) & 1;
        int e = (kin & 3) + 4 * ((kin >> 3) & 1);
        int lam = hh * 32 + o;
        wO[kk * 512 + lam * 8 + e] = (_Float16)W_out[i];
    }
    for (int i = tid; i < 32; i += NT) {      // b_out -> f32 D-layout [h][r]
        int hh = i >> 4, r = i & 15;
        int f = (r & 3) + 8 * (r >> 2) + 4 * hh;
        biasOut[i] = (f < 21) ? b_out[f] : 0.f;
    }
    __syncthreads();

    const int w = tid >> 6, lam = tid & 63;   // w in [0,12)
    const int col = lam & 31, h = lam >> 5;

    // hoist loop-invariant fragments: input-layer A, out-layer A, out bias
    half8 I[4], Ao[4];
    f32x16 bo;
    {
        const _Float16* p0 = wI + lam * 8;
        const _Float16* p1 = wI + 1024 + lam * 8;
        I[0] = ldh8(p0);       I[1] = ldh8(p0 + 512);
        I[2] = ldh8(p1);       I[3] = ldh8(p1 + 512);
        const _Float16* po = wO + lam * 8;
#pragma unroll
        for (int kk = 0; kk < 4; ++kk) Ao[kk] = ldh8(po + kk * 512);
        const float* pb = biasOut + h * 16;
#pragma unroll
        for (int i = 0; i < 4; ++i) {
            float4 a = *(const float4*)(pb + 4 * i);
            bo[4*i+0] = a.x; bo[4*i+1] = a.y; bo[4*i+2] = a.z; bo[4*i+3] = a.w;
        }
    }

    // persistent: 256 blocks x 128 tiles = 64 pairs; wave w takes pairs p = w + 12j
    // (waves 0-3 get 6 pairs, waves 4-11 get 5 — 12.5% tail, paid for 3-wave overlap)
    const int tbase = blockIdx.x * 128;
#pragma unroll 1
    for (int j = 0; j < 6; ++j) {
        int p = w + 12 * j;
        if (p >= 64) break;
        int rowA = (tbase + 2 * p) * 32 + col, rowB = rowA + 32;
        Frags BA, BB;
        load_x(x, rowA, h, BA);
        load_x(x, rowB, h, BB);

        half8 Fa0[4], Fa1[4], Fb0[4], Fb1[4];
        f32x16 CA0, CA1, CB0, CB1;
        f32x16 nE0, nE1, nO0, nO1;   // ping-pong bias buffers (even / odd layers)

        // ---- two-stream skewed pipeline; bias double-buffered in registers with a
        // full-chunk lead (mirrors the frag prefetch), consumed as MFMA C-init ----
        mfma_in_t(I, BA, CA0, CA1);          // A in-burst (4 MFMA)
        loadA4(wH, lam, Fa0, Fa1);           // frags l=0
        biasLoad(biasD, 0, h, nE0, nE1);     // bias l=0 (1-chunk lead)
        mfma_in_t(I, BB, CB0, CB1);          // B in-burst
        repack(CA0, CA1, BA);                // A repack
        SBAR();

#pragma unroll
        for (int l2 = 0; l2 < 5; ++l2) {
            const _Float16* b0 = wH + (2 * l2) * 4096;
            // layer 2*l2 (frags Fa, bias nE)
            mfma_hid4b(Fa0, Fa1, BA, nE0, nE1, CA0, CA1);   // A burst (8 MFMA)
            loadA4(b0 + 4096, lam, Fb0, Fb1);               // prefetch frags l+1
            biasLoad(biasD, 2 * l2 + 1, h, nO0, nO1);       // prefetch bias l+1 (nO dead)
            repack(CB0, CB1, BB);                           // B repack (prev layer)
            SBAR();
            mfma_hid4b(Fa0, Fa1, BB, nE0, nE1, CB0, CB1);   // B burst
            repack(CA0, CA1, BA);                           // A repack (layer l)
            SBAR();
            // layer 2*l2+1 (frags Fb, bias nO)
            mfma_hid4b(Fb0, Fb1, BA, nO0, nO1, CA0, CA1);   // A burst
            if (l2 < 4) {
                loadA4(b0 + 8192, lam, Fa0, Fa1);           // prefetch frags l+2
                biasLoad(biasD, 2 * l2 + 2, h, nE0, nE1);   // prefetch bias l+2 (nE dead)
            }
            repack(CB0, CB1, BB);                           // B repack (layer l)
            SBAR();
            mfma_hid4b(Fb0, Fb1, BB, nO0, nO1, CB0, CB1);   // B burst
            repack(CA0, CA1, BA);                           // A repack (layer l+1)
            SBAR();
        }

        // out layer (4 MFMA, C-init = bo)
        f32x16 CoA, CoB;
        mfma_out4(Ao, BA, bo, CoA);          // A burst
        repack(CB0, CB1, BB);                // B repack of layer 9
        SBAR();
        mfma_out4(Ao, BB, bo, CoB);          // B burst
        store_out(CoA, h, out, rowA);        // A sigmoid+store under B's burst
        store_out(CoB, h, out, rowB);
    }
}

extern "C" void kernel_launch(void* const* d_in, const int* in_sizes, int n_in,
                              void* d_out, int out_size, void* d_ws, size_t ws_size,
                              hipStream_t stream) {
    const float* x     = (const float*)d_in[0];
    const float* W_in  = (const float*)d_in[1];
    const float* b_in  = (const float*)d_in[2];
    const float* W_hid = (const float*)d_in[3];
    const float* b_hid = (const float*)d_in[4];
    const float* W_out = (const float*)d_in[5];
    const float* b_out = (const float*)d_in[6];
    float* out = (float*)d_out;
    mlp_fused<<<dim3(256), dim3(NT), 0, stream>>>(x, W_in, b_in, W_hid, b_hid, W_out, b_out, out);
}

// Round 24
// 110.523 us; speedup vs baseline: 4.1377x; 4.1377x over previous
//
#include <hip/hip_runtime.h>

#define DEV __device__ __forceinline__
#define SBAR() __builtin_amdgcn_sched_barrier(0)

typedef _Float16 half8 __attribute__((ext_vector_type(8)));
typedef _Float16 half2v __attribute__((ext_vector_type(2)));
typedef float f32x16 __attribute__((ext_vector_type(16)));
typedef int int4v __attribute__((ext_vector_type(4)));

DEV f32x16 mfma16(half8 a, half8 b, f32x16 c) {
    return __builtin_amdgcn_mfma_f32_32x32x16_f16(a, b, c, 0, 0, 0);
}
DEV half8 h8(int4v v) { return __builtin_bit_cast(half8, v); }
DEV half8 ldh8(const _Float16* p) { return *(const half8*)p; }
DEV int pkrtz(float a, float b) {
    auto t = __builtin_amdgcn_cvt_pkrtz(a, b);
    return __builtin_bit_cast(int, t);
}
// pack two f32 -> f16x2 (RTZ), then packed relu
DEV int relupk(float a, float b) {
    int p = pkrtz(a, b);
    half2v h = __builtin_bit_cast(half2v, p);
    half2v z = {(_Float16)0.f, (_Float16)0.f};
    h = __builtin_elementwise_max(h, z);   // v_pk_max_f16
    return __builtin_bit_cast(int, h);
}

DEV f32x16 zero16() {
    f32x16 z = {0.f,0.f,0.f,0.f,0.f,0.f,0.f,0.f,0.f,0.f,0.f,0.f,0.f,0.f,0.f,0.f};
    return z;
}

struct Frags { int4v c[4]; };  // activation B-fragments, K=64 (4 chunks of 16)

// sigma-repack (verified R18): weights' k-rows permuted by the involution
// sigma(k)=(k&3)+8*((k&7)>>2)+4*(k>>3) -> D-layout IS the next B-frag layout after pack.
DEV void repack(const f32x16& C0, const f32x16& C1, Frags& B) {
    int4v b0, b1, b2, b3;
#pragma unroll
    for (int q = 0; q < 4; ++q) {
        b0[q] = relupk(C0[2*q],     C0[2*q+1]);
        b1[q] = relupk(C0[8+2*q],   C0[9+2*q]);
        b2[q] = relupk(C1[2*q],     C1[2*q+1]);
        b3[q] = relupk(C1[8+2*q],   C1[9+2*q]);
    }
    B.c[0] = b0; B.c[1] = b1; B.c[2] = b2; B.c[3] = b3;
}

// 8 ds_read_b128: one hidden layer's A-fragments (4 chunks x 2 m-halves; no bias chunk)
DEV void loadA4(const _Float16* base, int lam, half8* A0, half8* A1) {
    const _Float16* p0 = base + lam * 8;
    const _Float16* p1 = base + 2048 + lam * 8;
#pragma unroll
    for (int kk = 0; kk < 4; ++kk) {
        A0[kk] = ldh8(p0 + kk * 512);
        A1[kk] = ldh8(p1 + kk * 512);
    }
}

// load layer-l bias fragment into ping-pong registers (f32 D-layout, broadcast reads).
DEV void biasLoad(const float* bD, int l, int h, f32x16& n0, f32x16& n1) {
    const float* p = bD + l * 64 + h * 16;
#pragma unroll
    for (int i = 0; i < 4; ++i) {
        float4 a = *(const float4*)(p + 4 * i);
        float4 b = *(const float4*)(p + 32 + 4 * i);
        n0[4*i+0] = a.x; n0[4*i+1] = a.y; n0[4*i+2] = a.z; n0[4*i+3] = a.w;
        n1[4*i+0] = b.x; n1[4*i+1] = b.y; n1[4*i+2] = b.z; n1[4*i+3] = b.w;
    }
}

// hidden layer burst: 8 MFMA, C-in of the first pair = prefetched bias (nb preserved
// so both streams can consume the same bias buffer)
DEV void mfma_hid4b(const half8* A0, const half8* A1, const Frags& Bx,
                    const f32x16& n0, const f32x16& n1, f32x16& C0, f32x16& C1) {
    __builtin_amdgcn_s_setprio(1);
    half8 b0 = h8(Bx.c[0]);
    C0 = mfma16(A0[0], b0, n0);
    C1 = mfma16(A1[0], b0, n1);
#pragma unroll
    for (int kk = 1; kk < 4; ++kk) {
        half8 b = h8(Bx.c[kk]);
        C0 = mfma16(A0[kk], b, C0);
        C1 = mfma16(A1[kk], b, C1);
    }
    __builtin_amdgcn_s_setprio(0);
}

// input layer burst: K=32 (b_in rides in x's k=28 slot), 4 MFMA, zero C-init
DEV void mfma_in_t(const half8* I, const Frags& Bx, f32x16& C0, f32x16& C1) {
    __builtin_amdgcn_s_setprio(1);
    C0 = mfma16(I[0], h8(Bx.c[0]), zero16());
    C1 = mfma16(I[2], h8(Bx.c[0]), zero16());
    C0 = mfma16(I[1], h8(Bx.c[1]), C0);
    C1 = mfma16(I[3], h8(Bx.c[1]), C1);
    __builtin_amdgcn_s_setprio(0);
}

// out layer burst: 4 MFMA, C-init = hoisted b_out fragment bo
DEV void mfma_out4(const half8* Ao, const Frags& Bx, const f32x16& bo, f32x16& C) {
    __builtin_amdgcn_s_setprio(1);
    C = mfma16(Ao[0], h8(Bx.c[0]), bo);
#pragma unroll
    for (int kk = 1; kk < 4; ++kk) C = mfma16(Ao[kk], h8(Bx.c[kk]), C);
    __builtin_amdgcn_s_setprio(0);
}

DEV void store_out(const f32x16& C, int h, float* __restrict__ out, int row) {
    float* o = out + row * 21;
#pragma unroll
    for (int r = 0; r < 16; ++r) {
        int f = (r & 3) + 8 * (r >> 2) + 4 * h;
        if (f < 21) o[f] = __builtin_amdgcn_rcpf(1.f + __expf(-C[r]));
    }
}

// raw x loads for one row (issued early; converted at next pair-iteration start)
struct RawX { float4 a, b, c, d; };
DEV void loadx_raw(const float* __restrict__ x, int row, int h, RawX& r) {
    const float* xr = x + row * 28;
    r.a = *(const float4*)(xr + 8 * h);
    r.b = *(const float4*)(xr + 8 * h + 4);
    r.c = *(const float4*)(xr + 16 + 8 * h);
    r.d = (h == 0) ? *(const float4*)(xr + 20) : make_float4(1.f, 0.f, 0.f, 0.f);
}
// identity k-order conversion (wI stored identity); k=28 slot carries 1.0
DEV void cvt_frags(const RawX& r, Frags& B) {
    int4v c0, c1;
    c0[0] = pkrtz(r.a.x, r.a.y); c0[1] = pkrtz(r.a.z, r.a.w);
    c0[2] = pkrtz(r.b.x, r.b.y); c0[3] = pkrtz(r.b.z, r.b.w);
    c1[0] = pkrtz(r.c.x, r.c.y); c1[1] = pkrtz(r.c.z, r.c.w);
    c1[2] = pkrtz(r.d.x, r.d.y); c1[3] = pkrtz(r.d.z, r.d.w);
    B.c[0] = c0; B.c[1] = c1;
}

#define NT 512

__global__ __attribute__((amdgpu_flat_work_group_size(NT, NT), amdgpu_waves_per_eu(2, 2)))
void mlp_fused(
    const float* __restrict__ x, const float* __restrict__ W_in, const float* __restrict__ b_in,
    const float* __restrict__ W_hid, const float* __restrict__ b_hid,
    const float* __restrict__ W_out, const float* __restrict__ b_out,
    float* __restrict__ out) {
    // LDS weights in f16, A-fragment order, SIGMA-permuted k (wI identity-k).
    __shared__ __align__(16) _Float16 wH[40960];  // 10 x 2 x 4 x 64 x 8 = 80 KB
    __shared__ __align__(16) _Float16 wI[2048];   // 2 x 2 x 64 x 8  (K=32, b_in in k=28)
    __shared__ __align__(16) _Float16 wO[2048];   // 4 x 64 x 8      (features 0..20)
    __shared__ __align__(16) float biasD[640];    // [l][half][h][r] f32 D-layout
    __shared__ __align__(16) float biasOut[32];   // [h][r] f32 D-layout

    const int tid = threadIdx.x;

    // zero phase (wH, biasD, biasOut are fully written by fill)
    for (int i = tid; i < 2048; i += NT) { wI[i] = (_Float16)0.f; wO[i] = (_Float16)0.f; }
    __syncthreads();

    // fill phase (coalesced global reads, scattered LDS writes)
    for (int i = tid; i < 40960; i += NT) {   // W_hid [l][kin][o], sigma-permuted k
        int o = i & 63, kin = (i >> 6) & 63, l = i >> 12;
        int m = o >> 5, kk = kin >> 4;
        int hh = (kin >> 2) & 1;
        int e = (kin & 3) + 4 * ((kin >> 3) & 1);
        int lam = hh * 32 + (o & 31);
        wH[l * 4096 + m * 2048 + kk * 512 + lam * 8 + e] = (_Float16)W_hid[i];
    }
    for (int i = tid; i < 640; i += NT) {     // b_hid -> f32 D-layout [l][half][h][r]
        int l = i >> 6, f = i & 63;
        int half = f >> 5, fin = f & 31;
        int hh = (fin >> 2) & 1, r = (fin & 3) + 4 * (fin >> 3);
        biasD[l * 64 + half * 32 + hh * 16 + r] = b_hid[i];
    }
    for (int i = tid; i < 1792; i += NT) {    // W_in [28][64], identity k
        int o = i & 63, kin = i >> 6;
        int m = o >> 5, kk = kin >> 4, hh = (kin >> 3) & 1, e = kin & 7;
        int lam = hh * 32 + (o & 31);
        wI[m * 1024 + kk * 512 + lam * 8 + e] = (_Float16)W_in[i];
    }
    for (int i = tid; i < 64; i += NT) {      // b_in -> wI k=28 slot: kk=1, hh=1, e=4
        int m = i >> 5;
        wI[m * 1024 + 512 + (32 + (i & 31)) * 8 + 4] = (_Float16)b_in[i];
    }
    for (int i = tid; i < 1344; i += NT) {    // W_out [64][21], sigma-permuted k
        int o = i % 21, kin = i / 21;
        int kk = kin >> 4;
        int hh = (kin >> 2) & 1;
        int e = (kin & 3) + 4 * ((kin >> 3) & 1);
        int lam = hh * 32 + o;
        wO[kk * 512 + lam * 8 + e] = (_Float16)W_out[i];
    }
    for (int i = tid; i < 32; i += NT) {      // b_out -> f32 D-layout [h][r]
        int hh = i >> 4, r = i & 15;
        int f = (r & 3) + 8 * (r >> 2) + 4 * hh;
        biasOut[i] = (f < 21) ? b_out[f] : 0.f;
    }
    __syncthreads();

    const int w = tid >> 6, lam = tid & 63;
    const int col = lam & 31, h = lam >> 5;

    // hoist loop-invariant fragments: input-layer A, out-layer A, out bias
    half8 I[4], Ao[4];
    f32x16 bo;
    {
        const _Float16* p0 = wI + lam * 8;
        const _Float16* p1 = wI + 1024 + lam * 8;
        I[0] = ldh8(p0);       I[1] = ldh8(p0 + 512);
        I[2] = ldh8(p1);       I[3] = ldh8(p1 + 512);
        const _Float16* po = wO + lam * 8;
#pragma unroll
        for (int kk = 0; kk < 4; ++kk) Ao[kk] = ldh8(po + kk * 512);
        const float* pb = biasOut + h * 16;
#pragma unroll
        for (int i = 0; i < 4; ++i) {
            float4 a = *(const float4*)(pb + 4 * i);
            bo[4*i+0] = a.x; bo[4*i+1] = a.y; bo[4*i+2] = a.z; bo[4*i+3] = a.w;
        }
    }

    // anti-phase stagger (kept from R22)
    if (w & 1) __builtin_amdgcn_s_sleep(4);

    // persistent: 256 blocks x 128 tiles; wave w owns tiles [w*16, w*16+16), 2 per iteration.
    // x-loads software-pipelined one pair-iteration ahead (HBM latency hidden under the
    // 12-layer stack instead of exposed at each iteration entry).
    const int tbase = blockIdx.x * 128;
    RawX rA, rB;
    {
        int rowA0 = (tbase + w * 16) * 32 + col;
        loadx_raw(x, rowA0, h, rA);
        loadx_raw(x, rowA0 + 32, h, rB);
    }
#pragma unroll 1
    for (int j = 0; j < 8; ++j) {
        int tA = tbase + w * 16 + 2 * j;
        int rowA = tA * 32 + col, rowB = rowA + 32;
        Frags BA, BB;
        cvt_frags(rA, BA);
        cvt_frags(rB, BB);
        if (j < 7) {                          // issue next pair's x loads now;
            loadx_raw(x, rowA + 64, h, rA);   // consumed after ~12 layers (~10 us cover)
            loadx_raw(x, rowB + 64, h, rB);
        }

        half8 Fa0[4], Fa1[4], Fb0[4], Fb1[4];
        f32x16 CA0, CA1, CB0, CB1;
        f32x16 nE0, nE1, nO0, nO1;   // ping-pong bias buffers (even / odd layers)

        // ---- two-stream skewed pipeline; bias double-buffered in registers with a
        // full-chunk lead (mirrors the frag prefetch), consumed as MFMA C-init ----
        mfma_in_t(I, BA, CA0, CA1);          // A in-burst (4 MFMA)
        loadA4(wH, lam, Fa0, Fa1);           // frags l=0
        biasLoad(biasD, 0, h, nE0, nE1);     // bias l=0 (1-chunk lead)
        mfma_in_t(I, BB, CB0, CB1);          // B in-burst
        repack(CA0, CA1, BA);                // A repack
        SBAR();

#pragma unroll
        for (int l2 = 0; l2 < 5; ++l2) {
            const _Float16* b0 = wH + (2 * l2) * 4096;
            // layer 2*l2 (frags Fa, bias nE)
            mfma_hid4b(Fa0, Fa1, BA, nE0, nE1, CA0, CA1);   // A burst (8 MFMA)
            loadA4(b0 + 4096, lam, Fb0, Fb1);               // prefetch frags l+1
            biasLoad(biasD, 2 * l2 + 1, h, nO0, nO1);       // prefetch bias l+1 (nO dead)
            repack(CB0, CB1, BB);                           // B repack (prev layer)
            SBAR();
            mfma_hid4b(Fa0, Fa1, BB, nE0, nE1, CB0, CB1);   // B burst
            repack(CA0, CA1, BA);                           // A repack (layer l)
            SBAR();
            // layer 2*l2+1 (frags Fb, bias nO)
            mfma_hid4b(Fb0, Fb1, BA, nO0, nO1, CA0, CA1);   // A burst
            if (l2 < 4) {
                loadA4(b0 + 8192, lam, Fa0, Fa1);           // prefetch frags l+2
                biasLoad(biasD, 2 * l2 + 2, h, nE0, nE1);   // prefetch bias l+2 (nE dead)
            }
            repack(CB0, CB1, BB);                           // B repack (layer l)
            SBAR();
            mfma_hid4b(Fb0, Fb1, BB, nO0, nO1, CB0, CB1);   // B burst
            repack(CA0, CA1, BA);                           // A repack (layer l+1)
            SBAR();
        }

        // out layer (4 MFMA, C-init = bo)
        f32x16 CoA, CoB;
        mfma_out4(Ao, BA, bo, CoA);          // A burst
        repack(CB0, CB1, BB);                // B repack of layer 9
        SBAR();
        mfma_out4(Ao, BB, bo, CoB);          // B burst
        store_out(CoA, h, out, rowA);        // A sigmoid+store under B's burst
        store_out(CoB, h, out, rowB);
    }
}

extern "C" void kernel_launch(void* const* d_in, const int* in_sizes, int n_in,
                              void* d_out, int out_size, void* d_ws, size_t ws_size,
                              hipStream_t stream) {
    const float* x     = (const float*)d_in[0];
    const float* W_in  = (const float*)d_in[1];
    const float* b_in  = (const float*)d_in[2];
    const float* W_hid = (const float*)d_in[3];
    const float* b_hid = (const float*)d_in[4];
    const float* W_out = (const float*)d_in[5];
    const float* b_out = (const float*)d_in[6];
    float* out = (float*)d_out;
    mlp_fused<<<dim3(256), dim3(NT), 0, stream>>>(x, W_in, b_in, W_hid, b_hid, W_out, b_out, out);
}

// Round 25
// 96.371 us; speedup vs baseline: 4.7453x; 1.1468x over previous
//
#include <hip/hip_runtime.h>

#define DEV __device__ __forceinline__
#define SBAR() __builtin_amdgcn_sched_barrier(0)

typedef _Float16 half8 __attribute__((ext_vector_type(8)));
typedef _Float16 half2v __attribute__((ext_vector_type(2)));
typedef float f32x16 __attribute__((ext_vector_type(16)));
typedef int int4v __attribute__((ext_vector_type(4)));

DEV f32x16 mfma16(half8 a, half8 b, f32x16 c) {
    return __builtin_amdgcn_mfma_f32_32x32x16_f16(a, b, c, 0, 0, 0);
}
DEV half8 h8(int4v v) { return __builtin_bit_cast(half8, v); }
DEV half8 ldh8(const _Float16* p) { return *(const half8*)p; }
DEV int pkrtz(float a, float b) {
    auto t = __builtin_amdgcn_cvt_pkrtz(a, b);
    return __builtin_bit_cast(int, t);
}
// pack two f32 -> f16x2 (RTZ), then packed relu
DEV int relupk(float a, float b) {
    int p = pkrtz(a, b);
    half2v h = __builtin_bit_cast(half2v, p);
    half2v z = {(_Float16)0.f, (_Float16)0.f};
    h = __builtin_elementwise_max(h, z);   // v_pk_max_f16
    return __builtin_bit_cast(int, h);
}

DEV f32x16 zero16() {
    f32x16 z = {0.f,0.f,0.f,0.f,0.f,0.f,0.f,0.f,0.f,0.f,0.f,0.f,0.f,0.f,0.f,0.f};
    return z;
}

struct Frags { int4v c[4]; };  // activation B-fragments, K=64 (4 chunks of 16)

// sigma-repack (verified R18): weights' k-rows permuted by the involution
// sigma(k)=(k&3)+8*((k&7)>>2)+4*(k>>3) -> D-layout IS the next B-frag layout after pack.
DEV void repack(const f32x16& C0, const f32x16& C1, Frags& B) {
    int4v b0, b1, b2, b3;
#pragma unroll
    for (int q = 0; q < 4; ++q) {
        b0[q] = relupk(C0[2*q],     C0[2*q+1]);
        b1[q] = relupk(C0[8+2*q],   C0[9+2*q]);
        b2[q] = relupk(C1[2*q],     C1[2*q+1]);
        b3[q] = relupk(C1[8+2*q],   C1[9+2*q]);
    }
    B.c[0] = b0; B.c[1] = b1; B.c[2] = b2; B.c[3] = b3;
}

// 8 ds_read_b128: one hidden layer's A-fragments (4 chunks x 2 m-halves; no bias chunk)
DEV void loadA4(const _Float16* base, int lam, half8* A0, half8* A1) {
    const _Float16* p0 = base + lam * 8;
    const _Float16* p1 = base + 2048 + lam * 8;
#pragma unroll
    for (int kk = 0; kk < 4; ++kk) {
        A0[kk] = ldh8(p0 + kk * 512);
        A1[kk] = ldh8(p1 + kk * 512);
    }
}

// load layer-l bias fragment into ping-pong registers (f32 D-layout, broadcast reads).
// Issued one full chunk before consumption -> LDS latency hidden under a burst.
DEV void biasLoad(const float* bD, int l, int h, f32x16& n0, f32x16& n1) {
    const float* p = bD + l * 64 + h * 16;
#pragma unroll
    for (int i = 0; i < 4; ++i) {
        float4 a = *(const float4*)(p + 4 * i);
        float4 b = *(const float4*)(p + 32 + 4 * i);
        n0[4*i+0] = a.x; n0[4*i+1] = a.y; n0[4*i+2] = a.z; n0[4*i+3] = a.w;
        n1[4*i+0] = b.x; n1[4*i+1] = b.y; n1[4*i+2] = b.z; n1[4*i+3] = b.w;
    }
}

// hidden layer burst: 8 MFMA, C-in of the first pair = prefetched bias (nb preserved
// so both streams can consume the same bias buffer)
DEV void mfma_hid4b(const half8* A0, const half8* A1, const Frags& Bx,
                    const f32x16& n0, const f32x16& n1, f32x16& C0, f32x16& C1) {
    __builtin_amdgcn_s_setprio(1);
    half8 b0 = h8(Bx.c[0]);
    C0 = mfma16(A0[0], b0, n0);
    C1 = mfma16(A1[0], b0, n1);
#pragma unroll
    for (int kk = 1; kk < 4; ++kk) {
        half8 b = h8(Bx.c[kk]);
        C0 = mfma16(A0[kk], b, C0);
        C1 = mfma16(A1[kk], b, C1);
    }
    __builtin_amdgcn_s_setprio(0);
}

// input layer burst: K=32 (b_in rides in x's k=28 slot), 4 MFMA, zero C-init
DEV void mfma_in_t(const half8* I, const Frags& Bx, f32x16& C0, f32x16& C1) {
    __builtin_amdgcn_s_setprio(1);
    C0 = mfma16(I[0], h8(Bx.c[0]), zero16());
    C1 = mfma16(I[2], h8(Bx.c[0]), zero16());
    C0 = mfma16(I[1], h8(Bx.c[1]), C0);
    C1 = mfma16(I[3], h8(Bx.c[1]), C1);
    __builtin_amdgcn_s_setprio(0);
}

// out layer burst: 4 MFMA, C-init = hoisted b_out fragment bo
DEV void mfma_out4(const half8* Ao, const Frags& Bx, const f32x16& bo, f32x16& C) {
    __builtin_amdgcn_s_setprio(1);
    C = mfma16(Ao[0], h8(Bx.c[0]), bo);
#pragma unroll
    for (int kk = 1; kk < 4; ++kk) C = mfma16(Ao[kk], h8(Bx.c[kk]), C);
    __builtin_amdgcn_s_setprio(0);
}

DEV void store_out(const f32x16& C, int h, float* __restrict__ out, int row) {
    float* o = out + row * 21;
#pragma unroll
    for (int r = 0; r < 16; ++r) {
        int f = (r & 3) + 8 * (r >> 2) + 4 * h;
        if (f < 21) o[f] = __builtin_amdgcn_rcpf(1.f + __expf(-C[r]));
    }
}

DEV void load_x(const float* __restrict__ x, int row, int h, Frags& B) {
    // identity k-order (wI stored identity); k=28 slot carries 1.0 (bias rides in wI row 28)
    const float* xr = x + row * 28;
    float4 fa = *(const float4*)(xr + 8 * h);
    float4 fb = *(const float4*)(xr + 8 * h + 4);
    float4 fc = *(const float4*)(xr + 16 + 8 * h);
    float4 fd = (h == 0) ? *(const float4*)(xr + 20) : make_float4(1.f, 0.f, 0.f, 0.f);
    int4v c0, c1;
    c0[0] = pkrtz(fa.x, fa.y); c0[1] = pkrtz(fa.z, fa.w);
    c0[2] = pkrtz(fb.x, fb.y); c0[3] = pkrtz(fb.z, fb.w);
    c1[0] = pkrtz(fc.x, fc.y); c1[1] = pkrtz(fc.z, fc.w);
    c1[2] = pkrtz(fd.x, fd.y); c1[3] = pkrtz(fd.z, fd.w);
    B.c[0] = c0; B.c[1] = c1;
}

#define NT 512

__global__ __attribute__((amdgpu_flat_work_group_size(NT, NT), amdgpu_waves_per_eu(2, 2)))
void mlp_fused(
    const float* __restrict__ x, const float* __restrict__ W_in, const float* __restrict__ b_in,
    const float* __restrict__ W_hid, const float* __restrict__ b_hid,
    const float* __restrict__ W_out, const float* __restrict__ b_out,
    float* __restrict__ out) {
    // LDS weights in f16, A-fragment order, SIGMA-permuted k (wI identity-k).
    // No bias chunks: wH [l][m][kk 0..3][lam][e]; b_hid in f32 D-layout biasD.
    __shared__ __align__(16) _Float16 wH[40960];  // 10 x 2 x 4 x 64 x 8 = 80 KB
    __shared__ __align__(16) _Float16 wI[2048];   // 2 x 2 x 64 x 8  (K=32, b_in in k=28)
    __shared__ __align__(16) _Float16 wO[2048];   // 4 x 64 x 8      (features 0..20)
    __shared__ __align__(16) float biasD[640];    // [l][half][h][r] f32 D-layout
    __shared__ __align__(16) float biasOut[32];   // [h][r] f32 D-layout

    const int tid = threadIdx.x;

    // zero phase (wH, biasD, biasOut are fully written by fill)
    for (int i = tid; i < 2048; i += NT) { wI[i] = (_Float16)0.f; wO[i] = (_Float16)0.f; }
    __syncthreads();

    // fill phase (coalesced global reads, scattered LDS writes)
    for (int i = tid; i < 40960; i += NT) {   // W_hid [l][kin][o], sigma-permuted k
        int o = i & 63, kin = (i >> 6) & 63, l = i >> 12;
        int m = o >> 5, kk = kin >> 4;
        int hh = (kin >> 2) & 1;
        int e = (kin & 3) + 4 * ((kin >> 3) & 1);
        int lam = hh * 32 + (o & 31);
        wH[l * 4096 + m * 2048 + kk * 512 + lam * 8 + e] = (_Float16)W_hid[i];
    }
    for (int i = tid; i < 640; i += NT) {     // b_hid -> f32 D-layout [l][half][h][r]
        int l = i >> 6, f = i & 63;
        int half = f >> 5, fin = f & 31;
        int hh = (fin >> 2) & 1, r = (fin & 3) + 4 * (fin >> 3);
        biasD[l * 64 + half * 32 + hh * 16 + r] = b_hid[i];
    }
    for (int i = tid; i < 1792; i += NT) {    // W_in [28][64], identity k
        int o = i & 63, kin = i >> 6;
        int m = o >> 5, kk = kin >> 4, hh = (kin >> 3) & 1, e = kin & 7;
        int lam = hh * 32 + (o & 31);
        wI[m * 1024 + kk * 512 + lam * 8 + e] = (_Float16)W_in[i];
    }
    for (int i = tid; i < 64; i += NT) {      // b_in -> wI k=28 slot: kk=1, hh=1, e=4
        int m = i >> 5;
        wI[m * 1024 + 512 + (32 + (i & 31)) * 8 + 4] = (_Float16)b_in[i];
    }
    for (int i = tid; i < 1344; i += NT) {    // W_out [64][21], sigma-permuted k
        int o = i % 21, kin = i / 21;
        int kk = kin >> 4;
        int hh = (kin >> 2) & 1;
        int e = (kin & 3) + 4 * ((kin >> 3) & 1);
        int lam = hh * 32 + o;
        wO[kk * 512 + lam * 8 + e] = (_Float16)W_out[i];
    }
    for (int i = tid; i < 32; i += NT) {      // b_out -> f32 D-layout [h][r]
        int hh = i >> 4, r = i & 15;
        int f = (r & 3) + 8 * (r >> 2) + 4 * hh;
        biasOut[i] = (f < 21) ? b_out[f] : 0.f;
    }
    __syncthreads();

    const int w = tid >> 6, lam = tid & 63;
    const int col = lam & 31, h = lam >> 5;

    // hoist loop-invariant fragments: input-layer A, out-layer A, out bias
    half8 I[4], Ao[4];
    f32x16 bo;
    {
        const _Float16* p0 = wI + lam * 8;
        const _Float16* p1 = wI + 1024 + lam * 8;
        I[0] = ldh8(p0);       I[1] = ldh8(p0 + 512);
        I[2] = ldh8(p1);       I[3] = ldh8(p1 + 512);
        const _Float16* po = wO + lam * 8;
#pragma unroll
        for (int kk = 0; kk < 4; ++kk) Ao[kk] = ldh8(po + kk * 512);
        const float* pb = biasOut + h * 16;
#pragma unroll
        for (int i = 0; i < 4; ++i) {
            float4 a = *(const float4*)(pb + 4 * i);
            bo[4*i+0] = a.x; bo[4*i+1] = a.y; bo[4*i+2] = a.z; bo[4*i+3] = a.w;
        }
    }

    // anti-phase stagger: odd waves start ~256 cyc late (harmless; kept from R22)
    if (w & 1) __builtin_amdgcn_s_sleep(4);

    // persistent: 256 blocks x 128 tiles; wave w owns tiles [w*16, w*16+16), 2 per iteration
    const int tbase = blockIdx.x * 128;
#pragma unroll 1
    for (int j = 0; j < 8; ++j) {
        int tA = tbase + w * 16 + 2 * j;
        int rowA = tA * 32 + col, rowB = rowA + 32;
        Frags BA, BB;
        load_x(x, rowA, h, BA);
        load_x(x, rowB, h, BB);

        half8 Fa0[4], Fa1[4], Fb0[4], Fb1[4];
        f32x16 CA0, CA1, CB0, CB1;
        f32x16 nE0, nE1, nO0, nO1;   // ping-pong bias buffers (even / odd layers)

        // ---- two-stream skewed pipeline; bias double-buffered in registers with a
        // full-chunk lead (mirrors the frag prefetch), consumed as MFMA C-init ----
        mfma_in_t(I, BA, CA0, CA1);          // A in-burst (4 MFMA)
        loadA4(wH, lam, Fa0, Fa1);           // frags l=0
        biasLoad(biasD, 0, h, nE0, nE1);     // bias l=0 (1-chunk lead)
        mfma_in_t(I, BB, CB0, CB1);          // B in-burst
        repack(CA0, CA1, BA);                // A repack
        SBAR();

#pragma unroll
        for (int l2 = 0; l2 < 5; ++l2) {
            const _Float16* b0 = wH + (2 * l2) * 4096;
            // layer 2*l2 (frags Fa, bias nE)
            mfma_hid4b(Fa0, Fa1, BA, nE0, nE1, CA0, CA1);   // A burst (8 MFMA)
            loadA4(b0 + 4096, lam, Fb0, Fb1);               // prefetch frags l+1
            biasLoad(biasD, 2 * l2 + 1, h, nO0, nO1);       // prefetch bias l+1 (nO dead)
            repack(CB0, CB1, BB);                           // B repack (prev layer)
            SBAR();
            mfma_hid4b(Fa0, Fa1, BB, nE0, nE1, CB0, CB1);   // B burst
            repack(CA0, CA1, BA);                           // A repack (layer l)
            SBAR();
            // layer 2*l2+1 (frags Fb, bias nO)
            mfma_hid4b(Fb0, Fb1, BA, nO0, nO1, CA0, CA1);   // A burst
            if (l2 < 4) {
                loadA4(b0 + 8192, lam, Fa0, Fa1);           // prefetch frags l+2
                biasLoad(biasD, 2 * l2 + 2, h, nE0, nE1);   // prefetch bias l+2 (nE dead)
            }
            repack(CB0, CB1, BB);                           // B repack (layer l)
            SBAR();
            mfma_hid4b(Fb0, Fb1, BB, nO0, nO1, CB0, CB1);   // B burst
            repack(CA0, CA1, BA);                           // A repack (layer l+1)
            SBAR();
        }

        // out layer (4 MFMA, C-init = bo)
        f32x16 CoA, CoB;
        mfma_out4(Ao, BA, bo, CoA);          // A burst
        repack(CB0, CB1, BB);                // B repack of layer 9
        SBAR();
        mfma_out4(Ao, BB, bo, CoB);          // B burst
        store_out(CoA, h, out, rowA);        // A sigmoid+store under B's burst
        store_out(CoB, h, out, rowB);
    }
}

extern "C" void kernel_launch(void* const* d_in, const int* in_sizes, int n_in,
                              void* d_out, int out_size, void* d_ws, size_t ws_size,
                              hipStream_t stream) {
    const float* x     = (const float*)d_in[0];
    const float* W_in  = (const float*)d_in[1];
    const float* b_in  = (const float*)d_in[2];
    const float* W_hid = (const float*)d_in[3];
    const float* b_hid = (const float*)d_in[4];
    const float* W_out = (const float*)d_in[5];
    const float* b_out = (const float*)d_in[6];
    float* out = (float*)d_out;
    mlp_fused<<<dim3(256), dim3(NT), 0, stream>>>(x, W_in, b_in, W_hid, b_hid, W_out, b_out, out);
}